// Round 13
// baseline (164.820 us; speedup 1.0000x reference)
//
#include <hip/hip_runtime.h>
#include <math.h>

#define LAMB    5.0f
#define LOG_PI  1.144729885849400f
#define L2E     1.4426950408889634f
#define LN2     0.6931471805599453f
#define LAM2E   7.213475204444817f   // LAMB * L2E

constexpr int HID = 100;
constexpr int KC  = 30;

typedef float    v2f __attribute__((ext_vector_type(2)));
typedef _Float16 h2  __attribute__((ext_vector_type(2)));

__device__ __forceinline__ v2f splat2(float s) { return (v2f){s, s}; }
__device__ __forceinline__ v2f fma2(v2f a, v2f b, v2f c) { return __builtin_elementwise_fma(a, b, c); }
__device__ __forceinline__ v2f max2(v2f a, v2f b) { return __builtin_elementwise_max(a, b); }

__device__ __forceinline__ float rcp_s(float x)  { return __builtin_amdgcn_rcpf(x); }
__device__ __forceinline__ float lg2_s(float x)  { return __builtin_amdgcn_logf(x); }   // log2
__device__ __forceinline__ float ex2_s(float x)  { return __builtin_amdgcn_exp2f(x); }  // 2^x
__device__ __forceinline__ v2f rcp2(v2f x)  { return (v2f){rcp_s(x.x), rcp_s(x.y)}; }
__device__ __forceinline__ v2f exp2v(v2f x) { return (v2f){ex2_s(x.x), ex2_s(x.y)}; }

// natural log1p (arg in (0,1] for softplus path), guarded for tiny u
__device__ __forceinline__ float log1p_s(float u) {
    float big = lg2_s(1.0f + u) * LN2;
    float sml = u * (1.0f - 0.5f * u);
    return (u > 1e-5f) ? big : sml;
}

// log2(1+u) elementwise, guarded for tiny u
__device__ __forceinline__ v2f log2_1p2(v2f u) {
    float bx = lg2_s(1.0f + u.x), by = lg2_s(1.0f + u.y);
    float sx = u.x * L2E * (1.0f - 0.5f * u.x);
    float sy = u.y * L2E * (1.0f - 0.5f * u.y);
    return (v2f){ (u.x > 1e-5f) ? bx : sx, (u.y > 1e-5f) ? by : sy };
}

// scalar softplus = max(v,0) + log1p(exp(-|v|))
__device__ __forceinline__ float softplus_s(float v) {
    float e = ex2_s(-fabsf(v) * L2E);
    return fmaxf(v, 0.f) + log1p_s(e);
}
__device__ __forceinline__ v2f softplus2(v2f v) {
    return (v2f){softplus_s(v.x), softplus_s(v.y)};
}

// ---- merged prep: rbf table (padded to 16 pairs) + f16 decoder pack +
//      encoder linear-part ----
__global__ __launch_bounds__(256) void prep(
    const float* __restrict__ Cc,   const float* __restrict__ Wc,
    const float* __restrict__ emw1, const float* __restrict__ emb1,
    const float* __restrict__ emw2,
    const float* __restrict__ esw1, const float* __restrict__ esb1,
    const float* __restrict__ esw2,
    const float* __restrict__ dmw1, const float* __restrict__ dmb1,
    const float* __restrict__ dmw2,
    const float* __restrict__ dfw1, const float* __restrict__ dfb1,
    const float* __restrict__ dfw2,
    float* __restrict__ rbfc, float* __restrict__ encl, h2* __restrict__ hb)
{
    int t = threadIdx.x;
    if (t < KC / 2) {
        int k = 2 * t;
        float c00 = Cc[2 * k],     c01 = Cc[2 * k + 1];
        float c10 = Cc[2 * k + 2], c11 = Cc[2 * k + 3];
        float* p = &rbfc[16 * t];
        p[0] = 2.0f * LAM2E * c00;  p[1] = 2.0f * LAM2E * c10;
        p[2] = 2.0f * LAM2E * c01;  p[3] = 2.0f * LAM2E * c11;
        p[4] = -LAM2E * (c00 * c00 + c01 * c01);
        p[5] = -LAM2E * (c10 * c10 + c11 * c11);
        p[6] = fmaxf(Wc[2 * k],     0.f);  p[7] = fmaxf(Wc[2 * k + 2], 0.f);
        p[8] = fmaxf(Wc[2 * k + 1], 0.f);  p[9] = fmaxf(Wc[2 * k + 3], 0.f);
        p[10] = 0.f; p[11] = 0.f; p[12] = 0.f; p[13] = 0.f; p[14] = 0.f; p[15] = 0.f;
    }
    if (t == 15) {               // zero pad pair (index 15) — contributes 0
        float* p = &rbfc[240];
        for (int q = 0; q < 16; ++q) p[q] = 0.f;
    }
    if (t == 32 || t == 33) {
        const float* w1 = (t == 32) ? emw1 : esw1;
        const float* b1 = (t == 32) ? emb1 : esb1;
        const float* w2 = (t == 32) ? emw2 : esw2;
        float A0 = 0.f, A1 = 0.f, B0 = 0.f, B1 = 0.f, C0 = 0.f, C1 = 0.f;
        for (int j = 0; j < HID; ++j) {
            float w20 = w2[2 * j], w21 = w2[2 * j + 1];
            A0 = fmaf(w1[j],       w20, A0);  A1 = fmaf(w1[j],       w21, A1);
            B0 = fmaf(w1[HID + j], w20, B0);  B1 = fmaf(w1[HID + j], w21, B1);
            C0 = fmaf(b1[j],       w20, C0);  C1 = fmaf(b1[j],       w21, C1);
        }
        float* q = &encl[(t - 32) * 6];
        q[0] = A0; q[1] = A1; q[2] = B0; q[3] = B1; q[4] = C0; q[5] = C1;
    }
    if (t >= 64 && t < 64 + HID / 2) {
        int tt = t - 64;
        int j = 2 * tt;
        h2* p = hb;
        p[tt]       = (h2){(_Float16)dmw1[j],        (_Float16)dmw1[j + 1]};
        p[50 + tt]  = (h2){(_Float16)dmw1[HID + j],  (_Float16)dmw1[HID + j + 1]};
        p[100 + tt] = (h2){(_Float16)dmb1[j],        (_Float16)dmb1[j + 1]};
        p[150 + tt] = (h2){(_Float16)dmw2[2 * j],    (_Float16)dmw2[2 * j + 2]};
        p[200 + tt] = (h2){(_Float16)dmw2[2 * j + 1],(_Float16)dmw2[2 * j + 3]};
    }
    if (t >= 128 && t < 128 + HID / 2) {
        int tt = t - 128;
        int j = 2 * tt;
        h2* p = hb + 256;
        p[tt]       = (h2){(_Float16)dfw1[j],        (_Float16)dfw1[j + 1]};
        p[50 + tt]  = (h2){(_Float16)dfw1[HID + j],  (_Float16)dfw1[HID + j + 1]};
        p[100 + tt] = (h2){(_Float16)dfb1[j],        (_Float16)dfb1[j + 1]};
        p[150 + tt] = (h2){(_Float16)dfw2[2 * j],    (_Float16)dfw2[2 * j + 2]};
        p[200 + tt] = (h2){(_Float16)dfw2[2 * j + 1],(_Float16)dfw2[2 * j + 3]};
    }
}

// two adjacent lanes (tid, tid^1) cooperatively process one sample
__global__ __launch_bounds__(256) void vae_main(
    const float* __restrict__ x,    const float* __restrict__ eps,
    const float* __restrict__ emw1, const float* __restrict__ emb1,
    const float* __restrict__ emw2, const float* __restrict__ emb2,
    const float* __restrict__ esw1, const float* __restrict__ esb1,
    const float* __restrict__ esw2, const float* __restrict__ esb2,
    const float* __restrict__ dmb2, const float* __restrict__ dfb2,
    const h2*    __restrict__ hb,
    const float* __restrict__ rbfc, const float* __restrict__ encl,
    float* __restrict__ out_xmu,   float* __restrict__ out_scale,
    float* __restrict__ out_z,     float* __restrict__ out_zmu,
    float* __restrict__ out_zstd,  float* __restrict__ partial,
    int n)
{
    const int tid  = blockIdx.x * 256 + threadIdx.x;
    const int s    = tid >> 1;          // sample index
    const int half = tid & 1;           // which half of hidden units

    float val = 0.0f;

    if (s < n) {
        const v2f xv = *(const v2f*)&x[2 * s];
        const v2f ev = *(const v2f*)&eps[2 * s];
        const v2f vx0 = splat2(xv.x), vx1 = splat2(xv.y);

        // ---- encoder MLPs (mu, std): f32, abs-trick, units [50h, 50h+50) ----
        const int o = half * 50;
        v2f accm = splat2(0.f), accs = splat2(0.f);
#pragma unroll 5
        for (int jj = 0; jj < 50; jj += 2) {
            const int j = o + jj;
            v2f w1a = *(const v2f*)&emw1[j];
            v2f w1b = *(const v2f*)&emw1[HID + j];
            v2f b1  = *(const v2f*)&emb1[j];
            v2f h   = fma2(vx0, w1a, fma2(vx1, w1b, b1));
            v2f w2a = *(const v2f*)&emw2[2 * j];
            v2f w2b = *(const v2f*)&emw2[2 * j + 2];
            accm = fma2(splat2(fabsf(h.x)), w2a, accm);
            accm = fma2(splat2(fabsf(h.y)), w2b, accm);

            v2f s1a = *(const v2f*)&esw1[j];
            v2f s1b = *(const v2f*)&esw1[HID + j];
            v2f sb1 = *(const v2f*)&esb1[j];
            v2f hs  = fma2(vx0, s1a, fma2(vx1, s1b, sb1));
            v2f d0 = *(const v2f*)&esw2[2 * j];
            v2f d1 = *(const v2f*)&esw2[2 * j + 2];
            accs = fma2(splat2(fabsf(hs.x)), d0, accs);
            accs = fma2(splat2(fabsf(hs.y)), d1, accs);
        }
        // combine halves (lane ^ 1)
        accm.x += __shfl_xor(accm.x, 1, 64);
        accm.y += __shfl_xor(accm.y, 1, 64);
        accs.x += __shfl_xor(accs.x, 1, 64);
        accs.y += __shfl_xor(accs.y, 1, 64);

        const v2f linm = fma2(splat2(xv.x), *(const v2f*)&encl[0],
                         fma2(splat2(xv.y), *(const v2f*)&encl[2],
                              *(const v2f*)&encl[4]));
        const v2f lins = fma2(splat2(xv.x), *(const v2f*)&encl[6],
                         fma2(splat2(xv.y), *(const v2f*)&encl[8],
                              *(const v2f*)&encl[10]));
        const v2f zmu  = splat2(0.5f) * (linm + accm) + *(const v2f*)&emb2[0];
        const v2f zstd = softplus2(splat2(0.5f) * (lins + accs) + *(const v2f*)&esb2[0]);
        const v2f sig  = (v2f){__builtin_amdgcn_sqrtf(zstd.x), __builtin_amdgcn_sqrtf(zstd.y)};
        const v2f z    = fma2(sig, ev, zmu);
        const float z0 = z.x, z1 = z.y;

        // ---- decoder MLPs: f16 layer1 + fdot2, unit-pairs [25h, 25h+25) ----
        const _Float16 z0f = (_Float16)z0;
        const _Float16 z1f = (_Float16)z1;
        const h2 z0h = (h2){z0f, z0f};
        const h2 z1h = (h2){z1f, z1f};
        const h2 hzero = {(_Float16)0.f, (_Float16)0.f};
        float dm0 = 0.f, dm1 = 0.f, dg0 = 0.f, dg1 = 0.f;
        const h2* hm = hb + half * 25;
        const h2* hf = hb + 256 + half * 25;
#pragma unroll 5
        for (int jj = 0; jj < 25; ++jj) {
            h2 pm = __builtin_elementwise_fma(z0h, hm[jj], hm[100 + jj]);
            pm = __builtin_elementwise_fma(z1h, hm[50 + jj], pm);
            pm = __builtin_elementwise_max(pm, hzero);
            dm0 = __builtin_amdgcn_fdot2(pm, hm[150 + jj], dm0, false);
            dm1 = __builtin_amdgcn_fdot2(pm, hm[200 + jj], dm1, false);

            h2 pf = __builtin_elementwise_fma(z0h, hf[jj], hf[100 + jj]);
            pf = __builtin_elementwise_fma(z1h, hf[50 + jj], pf);
            pf = __builtin_elementwise_max(pf, hzero);
            dg0 = __builtin_amdgcn_fdot2(pf, hf[150 + jj], dg0, false);
            dg1 = __builtin_amdgcn_fdot2(pf, hf[200 + jj], dg1, false);
        }
        dm0 += __shfl_xor(dm0, 1, 64);
        dm1 += __shfl_xor(dm1, 1, 64);
        dg0 += __shfl_xor(dg0, 1, 64);
        dg1 += __shfl_xor(dg1, 1, 64);
        const v2f xmu = (v2f){dm0, dm1} + *(const v2f*)&dmb2[0];
        const v2f df  = softplus2((v2f){dg0, dg1} + *(const v2f*)&dfb2[0]);

        // ---- RBF inverse-scale: 8 pair-iters per lane (table padded to 16) ----
        const float zz = z0 * z0 + z1 * z1;
        const v2f z0s = splat2(z0), z1s = splat2(z1);
        const v2f u0s = splat2(-LAM2E * zz);
        v2f acc0 = splat2(0.f), acc1 = splat2(0.f);
        const float* rb_base = rbfc + half * 128;   // 8 pairs * 16 floats
#pragma unroll
        for (int kk = 0; kk < 8; ++kk) {
            const float* p = &rb_base[16 * kk];
            v2f cx = *(const v2f*)&p[0];
            v2f cy = *(const v2f*)&p[2];
            v2f qq = *(const v2f*)&p[4];
            v2f w0p = *(const v2f*)&p[6];
            v2f w1p = *(const v2f*)&p[8];
            v2f arg = fma2(cx, z0s, fma2(cy, z1s, qq + u0s));
            v2f e = exp2v(arg);
            acc0 = fma2(e, w0p, acc0);
            acc1 = fma2(e, w1p, acc1);
        }
        float ia0 = acc0.x + acc0.y;
        float ia1 = acc1.x + acc1.y;
        ia0 += __shfl_xor(ia0, 1, 64);
        ia1 += __shfl_xor(ia1, 1, 64);
        const v2f ia = (v2f){ia0, ia1} + splat2(1e-10f);
        const v2f vscale = rcp2(ia);

        // ---- student-t log-prob + KL tail (duplicated in both lanes) ----
        const v2f a  = splat2(0.5f) * df;
        const v2f b  = a + splat2(3.0f);
        const v2f rb = rcp2(b);
        const v2f t  = splat2(0.5f) * rb;
        const v2f t2 = t * t;
        const v2f p  = t * (splat2(-0.25f) + t2 * (splat2(0.0416666667f) + t2 * splat2(-0.05f)));

        const v2f a1 = a + splat2(1.0f), a2 = a + splat2(2.0f);
        const v2f h1 = a + splat2(0.5f), h2v = a + splat2(1.5f), h3 = a + splat2(2.5f);
        const v2f pn = a * a1 * a2;
        const v2f pd = h1 * h2v * h3;
        const float rprod = (pn.x * pn.y) * rcp_s(pd.x * pd.y);

        const v2f rdf = rcp2(df);
        const float bb_dd = (b.x * b.y) * (rdf.x * rdf.y);
        const float S1 = lg2_s(bb_dd);
        const float S2 = lg2_s(rprod * (ia.x * ia.y));

        const v2f y  = (xv - xmu) * ia;
        const v2f u  = y * y * rdf;
        const v2f L2 = log2_1p2(u);
        const v2f dfp1 = df + splat2(1.0f);

        const float Szstd = lg2_s(zstd.x * zstd.y);

        const float A = 0.5f * S1 + S2
                      - 0.5f * (dfp1.x * L2.x + dfp1.y * L2.y)
                      + 0.5f * Szstd;
        const float ee = ev.x * ev.x + ev.y * ev.y;
        // both lanes hold identical val; halve so the pair sums to one sample
        val = 0.5f * (LN2 * A + (p.x + p.y) - LOG_PI + 0.5f * ee - 0.5f * zz);

        // ---- outputs: split stores between the halves ----
        if (half == 0) {
            *(v2f*)&out_xmu[2 * s]   = xmu;
            *(v2f*)&out_scale[2 * s] = vscale;
            *(v2f*)&out_z[2 * s]     = z;
        } else {
            *(v2f*)&out_zmu[2 * s]   = zmu;
            *(v2f*)&out_zstd[2 * s]  = zstd;
        }
    }

    // ---- per-wave reduction (no LDS, no barrier) ----
#pragma unroll
    for (int off = 32; off > 0; off >>= 1)
        val += __shfl_down(val, off, 64);
    if ((threadIdx.x & 63) == 0)
        partial[blockIdx.x * 4 + (threadIdx.x >> 6)] = val;
}

__global__ __launch_bounds__(256) void vae_reduce(
    const float* __restrict__ partial, int nprt, float* __restrict__ out, int n)
{
    __shared__ double sh[256];
    double acc = 0.0;
    for (int i = threadIdx.x; i < nprt; i += 256) acc += (double)partial[i];
    sh[threadIdx.x] = acc;
    __syncthreads();
#pragma unroll
    for (int s = 128; s > 0; s >>= 1) {
        if (threadIdx.x < s) sh[threadIdx.x] += sh[threadIdx.x + s];
        __syncthreads();
    }
    if (threadIdx.x == 0) out[0] = (float)(sh[0] / (double)n);
}

extern "C" void kernel_launch(void* const* d_in, const int* in_sizes, int n_in,
                              void* d_out, int out_size, void* d_ws, size_t ws_size,
                              hipStream_t stream) {
    const float* x    = (const float*)d_in[0];
    const float* eps  = (const float*)d_in[1];
    const float* emw1 = (const float*)d_in[2];
    const float* emb1 = (const float*)d_in[3];
    const float* emw2 = (const float*)d_in[4];
    const float* emb2 = (const float*)d_in[5];
    const float* esw1 = (const float*)d_in[6];
    const float* esb1 = (const float*)d_in[7];
    const float* esw2 = (const float*)d_in[8];
    const float* esb2 = (const float*)d_in[9];
    const float* dmw1 = (const float*)d_in[10];
    const float* dmb1 = (const float*)d_in[11];
    const float* dmw2 = (const float*)d_in[12];
    const float* dmb2 = (const float*)d_in[13];
    const float* dfw1 = (const float*)d_in[14];
    const float* dfb1 = (const float*)d_in[15];
    const float* dfw2 = (const float*)d_in[16];
    const float* dfb2 = (const float*)d_in[17];
    const float* Cc   = (const float*)d_in[18];
    const float* Wc   = (const float*)d_in[19];

    const int n = in_sizes[0] / 2;      // N samples
    float* out = (float*)d_out;
    float* out_elbo  = out;
    float* out_xmu   = out + 1;
    float* out_scale = out + 1 + 2 * (size_t)n;
    float* out_z     = out + 1 + 4 * (size_t)n;
    float* out_zmu   = out + 1 + 6 * (size_t)n;
    float* out_zstd  = out + 1 + 8 * (size_t)n;

    const int nblk2 = (2 * n + 255) / 256;            // 4096 blocks
    const int nprt  = nblk2 * 4;                      // wave-level partials

    float* partial = (float*)d_ws;                    // [nprt] floats (64 KB)
    float* rbfc    = (float*)d_ws + 16384;            // [256] floats (16 pairs)
    float* encl    = (float*)d_ws + 16704;            // [12] floats
    h2*    hb      = (h2*)((float*)d_ws + 17024);     // [512] half2

    prep<<<1, 256, 0, stream>>>(Cc, Wc,
                                emw1, emb1, emw2, esw1, esb1, esw2,
                                dmw1, dmb1, dmw2, dfw1, dfb1, dfw2,
                                rbfc, encl, hb);

    vae_main<<<nblk2, 256, 0, stream>>>(
        x, eps,
        emw1, emb1, emw2, emb2,
        esw1, esb1, esw2, esb2,
        dmb2, dfb2, hb, rbfc, encl,
        out_xmu, out_scale, out_z, out_zmu, out_zstd,
        partial, n);

    vae_reduce<<<1, 256, 0, stream>>>(partial, nprt, out_elbo, n);
}

// Round 14
// 43.497 us; speedup vs baseline: 3.7892x; 3.7892x over previous
//
#include <hip/hip_runtime.h>
#include <math.h>

#define LAMB    5.0f
#define LOG_PI  1.144729885849400f
#define L2E     1.4426950408889634f
#define LN2     0.6931471805599453f
#define LAM2E   7.213475204444817f   // LAMB * L2E

constexpr int HID = 100;
constexpr int KC  = 30;

typedef float    v2f __attribute__((ext_vector_type(2)));
typedef _Float16 h2  __attribute__((ext_vector_type(2)));

__device__ __forceinline__ v2f splat2(float s) { return (v2f){s, s}; }
__device__ __forceinline__ v2f fma2(v2f a, v2f b, v2f c) { return __builtin_elementwise_fma(a, b, c); }
__device__ __forceinline__ v2f max2(v2f a, v2f b) { return __builtin_elementwise_max(a, b); }

__device__ __forceinline__ float rcp_s(float x)  { return __builtin_amdgcn_rcpf(x); }
__device__ __forceinline__ float lg2_s(float x)  { return __builtin_amdgcn_logf(x); }   // log2
__device__ __forceinline__ float ex2_s(float x)  { return __builtin_amdgcn_exp2f(x); }  // 2^x
__device__ __forceinline__ v2f rcp2(v2f x)  { return (v2f){rcp_s(x.x), rcp_s(x.y)}; }
__device__ __forceinline__ v2f exp2v(v2f x) { return (v2f){ex2_s(x.x), ex2_s(x.y)}; }

// natural log1p (arg in (0,1] for softplus path), guarded for tiny u
__device__ __forceinline__ float log1p_s(float u) {
    float big = lg2_s(1.0f + u) * LN2;
    float sml = u * (1.0f - 0.5f * u);
    return (u > 1e-5f) ? big : sml;
}

// log2(1+u) elementwise, guarded for tiny u
__device__ __forceinline__ v2f log2_1p2(v2f u) {
    float bx = lg2_s(1.0f + u.x), by = lg2_s(1.0f + u.y);
    float sx = u.x * L2E * (1.0f - 0.5f * u.x);
    float sy = u.y * L2E * (1.0f - 0.5f * u.y);
    return (v2f){ (u.x > 1e-5f) ? bx : sx, (u.y > 1e-5f) ? by : sy };
}

// scalar softplus = max(v,0) + log1p(exp(-|v|))
__device__ __forceinline__ float softplus_s(float v) {
    float e = ex2_s(-fabsf(v) * L2E);
    return fmaxf(v, 0.f) + log1p_s(e);
}
__device__ __forceinline__ v2f softplus2(v2f v) {
    return (v2f){softplus_s(v.x), softplus_s(v.y)};
}

// ---- merged prep: rbf table + f16 decoder pack + encoder linear-part ----
// rbfc layout per pair kk (16 floats): cx(2), cy(2), q(2), w0(2), w1(2), pad(6)
// encl layout (12 floats): mu: A0,A1,B0,B1,C0,C1 ; std: same at +6
// hb layout (units of h2): [0..49]=w1 row0, [50..99]=w1 row1, [100..149]=b1,
//   [150..199]=w2 col0, [200..249]=w2 col1; m-MLP at hb, f-MLP at hb+256.
__global__ __launch_bounds__(256) void prep(
    const float* __restrict__ Cc,   const float* __restrict__ Wc,
    const float* __restrict__ emw1, const float* __restrict__ emb1,
    const float* __restrict__ emw2,
    const float* __restrict__ esw1, const float* __restrict__ esb1,
    const float* __restrict__ esw2,
    const float* __restrict__ dmw1, const float* __restrict__ dmb1,
    const float* __restrict__ dmw2,
    const float* __restrict__ dfw1, const float* __restrict__ dfb1,
    const float* __restrict__ dfw2,
    float* __restrict__ rbfc, float* __restrict__ encl, h2* __restrict__ hb)
{
    int t = threadIdx.x;
    if (t < KC / 2) {
        int k = 2 * t;
        float c00 = Cc[2 * k],     c01 = Cc[2 * k + 1];
        float c10 = Cc[2 * k + 2], c11 = Cc[2 * k + 3];
        float* p = &rbfc[16 * t];
        p[0] = 2.0f * LAM2E * c00;  p[1] = 2.0f * LAM2E * c10;
        p[2] = 2.0f * LAM2E * c01;  p[3] = 2.0f * LAM2E * c11;
        p[4] = -LAM2E * (c00 * c00 + c01 * c01);
        p[5] = -LAM2E * (c10 * c10 + c11 * c11);
        p[6] = fmaxf(Wc[2 * k],     0.f);  p[7] = fmaxf(Wc[2 * k + 2], 0.f);
        p[8] = fmaxf(Wc[2 * k + 1], 0.f);  p[9] = fmaxf(Wc[2 * k + 3], 0.f);
        p[10] = 0.f; p[11] = 0.f; p[12] = 0.f; p[13] = 0.f; p[14] = 0.f; p[15] = 0.f;
    }
    if (t == 32 || t == 33) {
        // encoder linear part: A = w1row0 . w2col, B = w1row1 . w2col, C = b1 . w2col
        const float* w1 = (t == 32) ? emw1 : esw1;
        const float* b1 = (t == 32) ? emb1 : esb1;
        const float* w2 = (t == 32) ? emw2 : esw2;
        float A0 = 0.f, A1 = 0.f, B0 = 0.f, B1 = 0.f, C0 = 0.f, C1 = 0.f;
        for (int j = 0; j < HID; ++j) {
            float w20 = w2[2 * j], w21 = w2[2 * j + 1];
            A0 = fmaf(w1[j],       w20, A0);  A1 = fmaf(w1[j],       w21, A1);
            B0 = fmaf(w1[HID + j], w20, B0);  B1 = fmaf(w1[HID + j], w21, B1);
            C0 = fmaf(b1[j],       w20, C0);  C1 = fmaf(b1[j],       w21, C1);
        }
        float* q = &encl[(t - 32) * 6];
        q[0] = A0; q[1] = A1; q[2] = B0; q[3] = B1; q[4] = C0; q[5] = C1;
    }
    if (t >= 64 && t < 64 + HID / 2) {
        int tt = t - 64;
        int j = 2 * tt;
        h2* p = hb;
        p[tt]       = (h2){(_Float16)dmw1[j],        (_Float16)dmw1[j + 1]};
        p[50 + tt]  = (h2){(_Float16)dmw1[HID + j],  (_Float16)dmw1[HID + j + 1]};
        p[100 + tt] = (h2){(_Float16)dmb1[j],        (_Float16)dmb1[j + 1]};
        p[150 + tt] = (h2){(_Float16)dmw2[2 * j],    (_Float16)dmw2[2 * j + 2]};
        p[200 + tt] = (h2){(_Float16)dmw2[2 * j + 1],(_Float16)dmw2[2 * j + 3]};
    }
    if (t >= 128 && t < 128 + HID / 2) {
        int tt = t - 128;
        int j = 2 * tt;
        h2* p = hb + 256;
        p[tt]       = (h2){(_Float16)dfw1[j],        (_Float16)dfw1[j + 1]};
        p[50 + tt]  = (h2){(_Float16)dfw1[HID + j],  (_Float16)dfw1[HID + j + 1]};
        p[100 + tt] = (h2){(_Float16)dfb1[j],        (_Float16)dfb1[j + 1]};
        p[150 + tt] = (h2){(_Float16)dfw2[2 * j],    (_Float16)dfw2[2 * j + 2]};
        p[200 + tt] = (h2){(_Float16)dfw2[2 * j + 1],(_Float16)dfw2[2 * j + 3]};
    }
}

__global__ __launch_bounds__(256) void vae_main(
    const float* __restrict__ x,    const float* __restrict__ eps,
    const float* __restrict__ emw1, const float* __restrict__ emb1,
    const float* __restrict__ emw2, const float* __restrict__ emb2,
    const float* __restrict__ esw1, const float* __restrict__ esb1,
    const float* __restrict__ esw2, const float* __restrict__ esb2,
    const float* __restrict__ dmb2, const float* __restrict__ dfb2,
    const h2*    __restrict__ hb,
    const float* __restrict__ rbfc, const float* __restrict__ encl,
    float* __restrict__ out_xmu,   float* __restrict__ out_scale,
    float* __restrict__ out_z,     float* __restrict__ out_zmu,
    float* __restrict__ out_zstd,  float* __restrict__ partial,
    int n)
{
    const int i = blockIdx.x * 256 + threadIdx.x;

    float val = 0.0f;

    if (i < n) {
        const v2f xv = *(const v2f*)&x[2 * i];
        const v2f ev = *(const v2f*)&eps[2 * i];
        const v2f vx0 = splat2(xv.x), vx1 = splat2(xv.y);

        // ---- encoder MLPs (mu, std): f32, relu -> abs trick ----
        // sum relu(p_j) w_j = 0.5*(A x0 + B x1 + C) + 0.5*sum |p_j| w_j
        v2f accm = splat2(0.f), accs = splat2(0.f);
#pragma unroll 10
        for (int j = 0; j < HID; j += 2) {
            v2f w1a = *(const v2f*)&emw1[j];
            v2f w1b = *(const v2f*)&emw1[HID + j];
            v2f b1  = *(const v2f*)&emb1[j];
            v2f h   = fma2(vx0, w1a, fma2(vx1, w1b, b1));
            v2f w2a = *(const v2f*)&emw2[2 * j];
            v2f w2b = *(const v2f*)&emw2[2 * j + 2];
            accm = fma2(splat2(fabsf(h.x)), w2a, accm);
            accm = fma2(splat2(fabsf(h.y)), w2b, accm);

            v2f s1a = *(const v2f*)&esw1[j];
            v2f s1b = *(const v2f*)&esw1[HID + j];
            v2f sb1 = *(const v2f*)&esb1[j];
            v2f hs  = fma2(vx0, s1a, fma2(vx1, s1b, sb1));
            v2f d0 = *(const v2f*)&esw2[2 * j];
            v2f d1 = *(const v2f*)&esw2[2 * j + 2];
            accs = fma2(splat2(fabsf(hs.x)), d0, accs);
            accs = fma2(splat2(fabsf(hs.y)), d1, accs);
        }
        const v2f linm = fma2(splat2(xv.x), *(const v2f*)&encl[0],
                         fma2(splat2(xv.y), *(const v2f*)&encl[2],
                              *(const v2f*)&encl[4]));
        const v2f lins = fma2(splat2(xv.x), *(const v2f*)&encl[6],
                         fma2(splat2(xv.y), *(const v2f*)&encl[8],
                              *(const v2f*)&encl[10]));
        const v2f zmu  = splat2(0.5f) * (linm + accm) + *(const v2f*)&emb2[0];
        const v2f zstd = softplus2(splat2(0.5f) * (lins + accs) + *(const v2f*)&esb2[0]);
        const v2f sig  = (v2f){__builtin_amdgcn_sqrtf(zstd.x), __builtin_amdgcn_sqrtf(zstd.y)};
        const v2f z    = fma2(sig, ev, zmu);
        const float z0 = z.x, z1 = z.y;

        // ---- decoder MLPs (mu, df): packed f16 layer1 + fdot2(f32-acc) layer2 ----
        const _Float16 z0f = (_Float16)z0;
        const _Float16 z1f = (_Float16)z1;
        const h2 z0h = (h2){z0f, z0f};
        const h2 z1h = (h2){z1f, z1f};
        const h2 hzero = {(_Float16)0.f, (_Float16)0.f};
        float dm0 = 0.f, dm1 = 0.f, dg0 = 0.f, dg1 = 0.f;
        const h2* hm = hb;
        const h2* hf = hb + 256;
#pragma unroll 10
        for (int jj = 0; jj < HID / 2; ++jj) {
            h2 pm = __builtin_elementwise_fma(z0h, hm[jj], hm[100 + jj]);
            pm = __builtin_elementwise_fma(z1h, hm[50 + jj], pm);
            pm = __builtin_elementwise_max(pm, hzero);
            dm0 = __builtin_amdgcn_fdot2(pm, hm[150 + jj], dm0, false);
            dm1 = __builtin_amdgcn_fdot2(pm, hm[200 + jj], dm1, false);

            h2 pf = __builtin_elementwise_fma(z0h, hf[jj], hf[100 + jj]);
            pf = __builtin_elementwise_fma(z1h, hf[50 + jj], pf);
            pf = __builtin_elementwise_max(pf, hzero);
            dg0 = __builtin_amdgcn_fdot2(pf, hf[150 + jj], dg0, false);
            dg1 = __builtin_amdgcn_fdot2(pf, hf[200 + jj], dg1, false);
        }
        const v2f xmu = (v2f){dm0, dm1} + *(const v2f*)&dmb2[0];
        const v2f df  = softplus2((v2f){dg0, dg1} + *(const v2f*)&dfb2[0]);

        // ---- RBF inverse-scale, pair-packed over k (f32, z exact) ----
        const float zz = z0 * z0 + z1 * z1;
        const v2f z0s = splat2(z0), z1s = splat2(z1);
        const v2f u0s = splat2(-LAM2E * zz);
        v2f acc0 = splat2(0.f), acc1 = splat2(0.f);
#pragma unroll
        for (int kk = 0; kk < KC / 2; ++kk) {
            const float* p = &rbfc[16 * kk];
            v2f cx = *(const v2f*)&p[0];
            v2f cy = *(const v2f*)&p[2];
            v2f qq = *(const v2f*)&p[4];
            v2f w0p = *(const v2f*)&p[6];
            v2f w1p = *(const v2f*)&p[8];
            v2f arg = fma2(cx, z0s, fma2(cy, z1s, qq + u0s));
            v2f e = exp2v(arg);
            acc0 = fma2(e, w0p, acc0);
            acc1 = fma2(e, w1p, acc1);
        }
        const v2f ia = (v2f){acc0.x + acc0.y, acc1.x + acc1.y} + splat2(1e-10f);
        const v2f vscale = rcp2(ia);

        // ---- student-t log-prob sum over dims, log-product fused ----
        // lp_d = g(a) - 0.5 ln df - 0.5 ln pi + ln ia - 0.5(df+1) ln(1+u)
        // g(a) = lgamma(a+1/2)-lgamma(a) = 0.5 ln b + ln r + p(t), b=a+3, t=1/(2b)
        const v2f a  = splat2(0.5f) * df;
        const v2f b  = a + splat2(3.0f);
        const v2f rb = rcp2(b);
        const v2f t  = splat2(0.5f) * rb;
        const v2f t2 = t * t;
        const v2f p  = t * (splat2(-0.25f) + t2 * (splat2(0.0416666667f) + t2 * splat2(-0.05f)));

        const v2f a1 = a + splat2(1.0f), a2 = a + splat2(2.0f);
        const v2f h1 = a + splat2(0.5f), h2v = a + splat2(1.5f), h3 = a + splat2(2.5f);
        const v2f pn = a * a1 * a2;
        const v2f pd = h1 * h2v * h3;
        const float rprod = (pn.x * pn.y) * rcp_s(pd.x * pd.y);

        const v2f rdf = rcp2(df);
        const float bb_dd = (b.x * b.y) * (rdf.x * rdf.y);
        const float S1 = lg2_s(bb_dd);                       // log2(b.x b.y / (df.x df.y))
        const float S2 = lg2_s(rprod * (ia.x * ia.y));       // log2(r-prod * ia-prod)

        const v2f y  = (xv - xmu) * ia;
        const v2f u  = y * y * rdf;
        const v2f L2 = log2_1p2(u);
        const v2f dfp1 = df + splat2(1.0f);

        const float Szstd = lg2_s(zstd.x * zstd.y);          // for KL

        const float A = 0.5f * S1 + S2
                      - 0.5f * (dfp1.x * L2.x + dfp1.y * L2.y)
                      + 0.5f * Szstd;
        const float ee = ev.x * ev.x + ev.y * ev.y;
        val = LN2 * A + (p.x + p.y) - LOG_PI + 0.5f * ee - 0.5f * zz;

        // ---- outputs ----
        *(v2f*)&out_xmu[2 * i]   = xmu;
        *(v2f*)&out_scale[2 * i] = vscale;
        *(v2f*)&out_z[2 * i]     = z;
        *(v2f*)&out_zmu[2 * i]   = zmu;
        *(v2f*)&out_zstd[2 * i]  = zstd;
    }

    // ---- deterministic block reduction of val ----
#pragma unroll
    for (int off = 32; off > 0; off >>= 1)
        val += __shfl_down(val, off, 64);

    __shared__ float wsum[4];
    const int lane = threadIdx.x & 63;
    const int wid  = threadIdx.x >> 6;
    if (lane == 0) wsum[wid] = val;
    __syncthreads();
    if (threadIdx.x == 0)
        partial[blockIdx.x] = (wsum[0] + wsum[1]) + (wsum[2] + wsum[3]);
}

__global__ __launch_bounds__(256) void vae_reduce(
    const float* __restrict__ partial, int nblk, float* __restrict__ out, int n)
{
    __shared__ double sh[256];
    double acc = 0.0;
    for (int i = threadIdx.x; i < nblk; i += 256) acc += (double)partial[i];
    sh[threadIdx.x] = acc;
    __syncthreads();
#pragma unroll
    for (int s = 128; s > 0; s >>= 1) {
        if (threadIdx.x < s) sh[threadIdx.x] += sh[threadIdx.x + s];
        __syncthreads();
    }
    if (threadIdx.x == 0) out[0] = (float)(sh[0] / (double)n);
}

extern "C" void kernel_launch(void* const* d_in, const int* in_sizes, int n_in,
                              void* d_out, int out_size, void* d_ws, size_t ws_size,
                              hipStream_t stream) {
    const float* x    = (const float*)d_in[0];
    const float* eps  = (const float*)d_in[1];
    const float* emw1 = (const float*)d_in[2];
    const float* emb1 = (const float*)d_in[3];
    const float* emw2 = (const float*)d_in[4];
    const float* emb2 = (const float*)d_in[5];
    const float* esw1 = (const float*)d_in[6];
    const float* esb1 = (const float*)d_in[7];
    const float* esw2 = (const float*)d_in[8];
    const float* esb2 = (const float*)d_in[9];
    const float* dmw1 = (const float*)d_in[10];
    const float* dmb1 = (const float*)d_in[11];
    const float* dmw2 = (const float*)d_in[12];
    const float* dmb2 = (const float*)d_in[13];
    const float* dfw1 = (const float*)d_in[14];
    const float* dfb1 = (const float*)d_in[15];
    const float* dfw2 = (const float*)d_in[16];
    const float* dfb2 = (const float*)d_in[17];
    const float* Cc   = (const float*)d_in[18];
    const float* Wc   = (const float*)d_in[19];

    const int n = in_sizes[0] / 2;      // N samples
    float* out = (float*)d_out;
    float* out_elbo  = out;
    float* out_xmu   = out + 1;
    float* out_scale = out + 1 + 2 * (size_t)n;
    float* out_z     = out + 1 + 4 * (size_t)n;
    float* out_zmu   = out + 1 + 6 * (size_t)n;
    float* out_zstd  = out + 1 + 8 * (size_t)n;

    float* partial = (float*)d_ws;                    // [nblk] floats
    float* rbfc    = (float*)d_ws + 4096;             // [240] floats
    float* encl    = (float*)d_ws + 6144;             // [12] floats
    h2*    hb      = (h2*)((float*)d_ws + 8192);      // [512] half2

    const int nblk = (n + 255) / 256;

    prep<<<1, 256, 0, stream>>>(Cc, Wc,
                                emw1, emb1, emw2, esw1, esb1, esw2,
                                dmw1, dmb1, dmw2, dfw1, dfb1, dfw2,
                                rbfc, encl, hb);

    vae_main<<<nblk, 256, 0, stream>>>(
        x, eps,
        emw1, emb1, emw2, emb2,
        esw1, esb1, esw2, esb2,
        dmb2, dfb2, hb, rbfc, encl,
        out_xmu, out_scale, out_z, out_zmu, out_zstd,
        partial, n);

    vae_reduce<<<1, 256, 0, stream>>>(partial, nblk, out_elbo, n);
}